// Round 20
// baseline (552.590 us; speedup 1.0000x reference)
//
#include <hip/hip_runtime.h>

#define IN_DIM  512
#define HID_DIM 256
#define OUT_DIM 64
#define KPROP   5
#define ALPHA   0.1f

#define BKT_SHIFT 9            // 512 dst nodes per bucket
#define PART_EPB  8192         // edges per partition block

typedef short short8v __attribute__((ext_vector_type(8)));
typedef float f32x4   __attribute__((ext_vector_type(4)));
typedef float f32x2   __attribute__((ext_vector_type(2)));

__device__ __forceinline__ unsigned short f2bf(float f) {
    unsigned u = __builtin_bit_cast(unsigned, f);
    unsigned r = (u + 0x7FFFu + ((u >> 16) & 1u)) >> 16;
    return (unsigned short)r;
}

// ---------------- bucket-level edge count ----------------
__global__ __launch_bounds__(256) void bucket_count_kernel(const int* __restrict__ ei, int E,
                                                           int* __restrict__ bucketCnt) {
    __shared__ int hist[256];
    int t = threadIdx.x;
    hist[t] = 0;
    __syncthreads();
    int e0 = blockIdx.x * PART_EPB;
#pragma unroll 4
    for (int i = 0; i < PART_EPB / 256; ++i) {
        int e = e0 + i * 256 + t;
        if (e < E) atomicAdd(&hist[ei[E + e] >> BKT_SHIFT], 1);
    }
    __syncthreads();
    if (hist[t] > 0) atomicAdd(&bucketCnt[t], hist[t]);
}

// ---------------- bucket scan (1 block) ----------------
__global__ __launch_bounds__(256) void bucket_scan_kernel(const int* __restrict__ bucketCnt,
                                                          int* __restrict__ bucketBase,
                                                          int* __restrict__ bucketFill,
                                                          int* __restrict__ indptr,
                                                          int E, int N) {
    __shared__ int sm[256];
    int t = threadIdx.x;
    int v = bucketCnt[t];
    sm[t] = v;
    __syncthreads();
    for (int off = 1; off < 256; off <<= 1) {
        int add = 0;
        if (t >= off) add = sm[t - off];
        __syncthreads();
        if (t >= off) sm[t] += add;
        __syncthreads();
    }
    int base = sm[t] - v;
    bucketBase[t] = base;
    bucketFill[t] = base;
    if (t == 0) indptr[N] = E;
}

// ---------------- partition; packed = (dst&511)<<17 | src ----------------
__global__ __launch_bounds__(256) void partition_kernel(const int* __restrict__ ei, int E,
                                                        int* __restrict__ bucketFill,
                                                        int* __restrict__ packed) {
    __shared__ int hist[256];
    __shared__ int base[256];
    int t = threadIdx.x;
    int e0 = blockIdx.x * PART_EPB;
    hist[t] = 0;
    __syncthreads();
#pragma unroll 4
    for (int i = 0; i < PART_EPB / 256; ++i) {
        int e = e0 + i * 256 + t;
        if (e < E) atomicAdd(&hist[ei[E + e] >> BKT_SHIFT], 1);
    }
    __syncthreads();
    int cnt = hist[t];
    if (cnt > 0) base[t] = atomicAdd(&bucketFill[t], cnt);
    __syncthreads();
#pragma unroll 4
    for (int i = 0; i < PART_EPB / 256; ++i) {
        int e = e0 + i * 256 + t;
        if (e < E) {
            int dst = ei[E + e];
            int src = ei[e];
            int b = dst >> BKT_SHIFT;
            int pos = atomicAdd(&base[b], 1);
            packed[pos] = ((dst & 511) << 17) | src;
        }
    }
}

// ---------------- fused per-bucket: node hist + indptr + dinv + scatter ----------------
__global__ __launch_bounds__(256) void fine_kernel(const int* __restrict__ packed,
                                                   const int* __restrict__ bucketBase,
                                                   const int* __restrict__ bucketCnt,
                                                   int* __restrict__ csr_row,
                                                   int* __restrict__ indptr,
                                                   float* __restrict__ dinv, int N) {
    __shared__ int cnt[512];
    __shared__ int pre[512];
    __shared__ int fill[512];
    __shared__ int sm[256];
    int b = blockIdx.x;
    int t = threadIdx.x;
    int d0 = b << BKT_SHIFT;
    int nd = N - d0;
    if (nd > 512) nd = 512;
    cnt[t] = 0; cnt[t + 256] = 0;
    fill[t] = 0; fill[t + 256] = 0;
    __syncthreads();
    int beg = bucketBase[b];
    int end = beg + bucketCnt[b];
    for (int e = beg + t; e < end; e += 256)
        atomicAdd(&cnt[((unsigned)packed[e]) >> 17], 1);
    __syncthreads();
    int c0 = cnt[2 * t], c1 = cnt[2 * t + 1];
    int s = c0 + c1;
    sm[t] = s;
    __syncthreads();
    for (int off = 1; off < 256; off <<= 1) {
        int add = 0;
        if (t >= off) add = sm[t - off];
        __syncthreads();
        if (t >= off) sm[t] += add;
        __syncthreads();
    }
    int ex = sm[t] - s;
    pre[2 * t] = ex;
    pre[2 * t + 1] = ex + c0;
    __syncthreads();
    for (int dl = t; dl < nd; dl += 256) {
        indptr[d0 + dl] = beg + pre[dl];
        dinv[d0 + dl] = rsqrtf((float)(cnt[dl] + 1));
    }
    for (int e = beg + t; e < end; e += 256) {
        unsigned p = (unsigned)packed[e];
        int dl = (int)(p >> 17);
        int src = (int)(p & 0x1FFFFu);
        int pos = beg + pre[dl] + atomicAdd(&fill[dl], 1);
        csr_row[pos] = src;
    }
}

// ---------------- weight prep ----------------
__global__ __launch_bounds__(256) void prep_w1_kernel(const float* __restrict__ W1,
                                                      unsigned short* __restrict__ w1p) {
    int idx = blockIdx.x * 256 + threadIdx.x;
    int q = idx >> 14;
    int rem = idx & 16383;
    int c = rem >> 6, j = rem & 63;
    w1p[idx] = f2bf(W1[(size_t)(q * 64 + j) * HID_DIM + c]);
}

__global__ __launch_bounds__(256) void prep_w2_kernel(const float* __restrict__ W2,
                                                      unsigned short* __restrict__ w2p) {
    int idx = blockIdx.x * 256 + threadIdx.x;
    int c = idx >> 8, k = idx & 255;
    w2p[idx] = f2bf(W2[(size_t)k * OUT_DIM + c]);
}

// ---------------- MFMA MLP: r16 structure; epilogue writes fp8 hs ----------------
struct __align__(16) MlpSmem {
    union {
        struct {
            unsigned short xs[64][72];     // 9216 B
            unsigned short ws[256][72];    // 36864 B
        } p1;
        struct {
            unsigned short hid[64][264];   // 33792 B
            unsigned short w2s[32][264];   // 16896 B
        } p2;                              // 50688 B LDS -> 3 blocks/CU
    };
};

__device__ __forceinline__ float4 ldx1(const float* __restrict__ x, int row0, int N,
                                       int t, int i, int q) {
    int e = t * 4 + i * 1024;
    int r = e >> 6, j = e & 63;
    if (row0 + r < N) return *(const float4*)&x[(size_t)(row0 + r) * IN_DIM + q * 64 + j];
    return make_float4(0.f, 0.f, 0.f, 0.f);
}

__global__ __launch_bounds__(256, 3) void mlp_mfma_kernel(const float* __restrict__ x,
                                                          const unsigned short* __restrict__ w1p,
                                                          const float* __restrict__ b1,
                                                          const unsigned short* __restrict__ w2p,
                                                          const float* __restrict__ b2,
                                                          const float* __restrict__ dinv,
                                                          float* __restrict__ h0,
                                                          unsigned char* __restrict__ hs,
                                                          int N) {
    __shared__ MlpSmem sm;
    int t = threadIdx.x;
    int w = t >> 6, l = t & 63;
    int l15 = l & 15, l4 = l >> 4;
    int wr0 = w * 16;
    int row0 = blockIdx.x * 64;

    f32x4 acc[16];
#pragma unroll
    for (int i = 0; i < 16; ++i) acc[i] = (f32x4){0.f, 0.f, 0.f, 0.f};

    float4 xr0, xr1, xr2, xr3;
    uint4 wv0, wv1, wv2, wv3, wv4, wv5, wv6, wv7;

#define LOADX(q) do { \
        xr0 = ldx1(x, row0, N, t, 0, (q)); \
        xr1 = ldx1(x, row0, N, t, 1, (q)); \
        xr2 = ldx1(x, row0, N, t, 2, (q)); \
        xr3 = ldx1(x, row0, N, t, 3, (q)); \
    } while (0)
#define LOADW(q) do { \
        const unsigned short* _s = w1p + (q) * 16384; \
        wv0 = *(const uint4*)&_s[t * 8 + 0 * 2048]; \
        wv1 = *(const uint4*)&_s[t * 8 + 1 * 2048]; \
        wv2 = *(const uint4*)&_s[t * 8 + 2 * 2048]; \
        wv3 = *(const uint4*)&_s[t * 8 + 3 * 2048]; \
        wv4 = *(const uint4*)&_s[t * 8 + 4 * 2048]; \
        wv5 = *(const uint4*)&_s[t * 8 + 5 * 2048]; \
        wv6 = *(const uint4*)&_s[t * 8 + 6 * 2048]; \
        wv7 = *(const uint4*)&_s[t * 8 + 7 * 2048]; \
    } while (0)
#define STX(i, v) do { \
        int e = t * 4 + (i) * 1024; \
        int r = e >> 6, j = e & 63; \
        unsigned u0 = (unsigned)f2bf((v).x) | ((unsigned)f2bf((v).y) << 16); \
        unsigned u1 = (unsigned)f2bf((v).z) | ((unsigned)f2bf((v).w) << 16); \
        *(uint2*)&sm.p1.xs[r][j] = make_uint2(u0, u1); \
    } while (0)
#define STW(i, v) do { \
        int e = t * 8 + (i) * 2048; \
        int c = e >> 6, j = e & 63; \
        *(uint4*)&sm.p1.ws[c][j] = (v); \
    } while (0)

    LOADX(0);
    LOADW(0);

    for (int q = 0; q < 8; ++q) {
        __syncthreads();
        STX(0, xr0); STX(1, xr1); STX(2, xr2); STX(3, xr3);
        STW(0, wv0); STW(1, wv1); STW(2, wv2); STW(3, wv3);
        STW(4, wv4); STW(5, wv5); STW(6, wv6); STW(7, wv7);
        __syncthreads();
        if (q < 7) {
            LOADX(q + 1);
            LOADW(q + 1);
        }
#pragma unroll
        for (int s = 0; s < 2; ++s) {
            short8v a = *(const short8v*)&sm.p1.xs[wr0 + l15][s * 32 + l4 * 8];
#pragma unroll
            for (int tc = 0; tc < 16; ++tc) {
                short8v b = *(const short8v*)&sm.p1.ws[tc * 16 + l15][s * 32 + l4 * 8];
                acc[tc] = __builtin_amdgcn_mfma_f32_16x16x32_bf16(a, b, acc[tc], 0, 0, 0);
            }
        }
    }
    __syncthreads();  // xs/ws dead; p2 overlay begins

#pragma unroll
    for (int tc = 0; tc < 16; ++tc) {
        float bv = b1[tc * 16 + l15];
#pragma unroll
        for (int i = 0; i < 4; ++i) {
            float v = fmaxf(acc[tc][i] + bv, 0.f);
            sm.p2.hid[wr0 + l4 * 4 + i][tc * 16 + l15] = f2bf(v);
        }
    }

    f32x4 acc2[4];
#pragma unroll
    for (int i = 0; i < 4; ++i) acc2[i] = (f32x4){0.f, 0.f, 0.f, 0.f};

#pragma unroll
    for (int hf = 0; hf < 2; ++hf) {
#pragma unroll
        for (int i = 0; i < 4; ++i) {
            int e = t * 8 + i * 2048;
            int c = e >> 8, k = e & 255;
            *(uint4*)&sm.p2.w2s[c][k] = *(const uint4*)&w2p[hf * 8192 + e];
        }
        __syncthreads();
#pragma unroll
        for (int s = 0; s < 8; ++s) {
            short8v a = *(const short8v*)&sm.p2.hid[wr0 + l15][s * 32 + l4 * 8];
#pragma unroll
            for (int tcl = 0; tcl < 2; ++tcl) {
                short8v b = *(const short8v*)&sm.p2.w2s[tcl * 16 + l15][s * 32 + l4 * 8];
                acc2[hf * 2 + tcl] =
                    __builtin_amdgcn_mfma_f32_16x16x32_bf16(a, b, acc2[hf * 2 + tcl], 0, 0, 0);
            }
        }
        __syncthreads();
    }

    // epilogue2: h0 (fp32) + hs = fp8_e4m3(dinv * h0)
#pragma unroll
    for (int i = 0; i < 4; ++i) {
        int row = row0 + wr0 + l4 * 4 + i;
        if (row < N) {
            float dv = dinv[row];
#pragma unroll
            for (int tc = 0; tc < 4; ++tc) {
                float v = acc2[tc][i] + b2[tc * 16 + l15];
                h0[(size_t)row * OUT_DIM + tc * 16 + l15] = v;
                float sv = dv * v;
                int pk = __builtin_amdgcn_cvt_pk_fp8_f32(sv, sv, 0, false);
                hs[(size_t)row * OUT_DIM + tc * 16 + l15] = (unsigned char)(pk & 0xFF);
            }
        }
    }
#undef LOADX
#undef LOADW
#undef STX
#undef STW
}

// ---------------- propagation, fp8 rows, 4-lane/row uint4 (16 rows per gather instr) ----
// r18/r19 trend: rows-in-flight per instruction is the lever. Lane = (q16 = l>>2
// edge-slot, lf16 = l&3 feature-16-tuple); lane loads uint4 (16 fp8, 16B =
// coalescing sweet spot); one gather instruction covers 16 rows; 32-edge trip =
// 2 idx loads + 2 gathers (32 rows in flight, half the VMEM instructions of r19).
__global__ __launch_bounds__(256) void prop_fp8_kernel(const unsigned char* __restrict__ hs,
                                                       const float* __restrict__ h0,
                                                       const float* __restrict__ dinv,
                                                       const int* __restrict__ csr_row,
                                                       const int* __restrict__ indptr,
                                                       unsigned char* __restrict__ hs_out,
                                                       float* __restrict__ hfin,
                                                       int last, int N) {
    int node = blockIdx.x * 4 + (threadIdx.x >> 6);
    if (node >= N) return;
    int l = threadIdx.x & 63;
    int q16 = l >> 2, lf16 = l & 3;
    const uint4* H4 = (const uint4*)hs;   // [N][4] uint4
    int beg = indptr[node], end = indptr[node + 1];
    float c[16];
#pragma unroll
    for (int i = 0; i < 16; ++i) c[i] = 0.f;
#define ACCU4(u4) do { \
        f32x2 _p; \
        _p = __builtin_amdgcn_cvt_pk_f32_fp8((int)(u4).x, false); c[0] += _p[0];  c[1] += _p[1]; \
        _p = __builtin_amdgcn_cvt_pk_f32_fp8((int)(u4).x, true);  c[2] += _p[0];  c[3] += _p[1]; \
        _p = __builtin_amdgcn_cvt_pk_f32_fp8((int)(u4).y, false); c[4] += _p[0];  c[5] += _p[1]; \
        _p = __builtin_amdgcn_cvt_pk_f32_fp8((int)(u4).y, true);  c[6] += _p[0];  c[7] += _p[1]; \
        _p = __builtin_amdgcn_cvt_pk_f32_fp8((int)(u4).z, false); c[8] += _p[0];  c[9] += _p[1]; \
        _p = __builtin_amdgcn_cvt_pk_f32_fp8((int)(u4).z, true);  c[10] += _p[0]; c[11] += _p[1]; \
        _p = __builtin_amdgcn_cvt_pk_f32_fp8((int)(u4).w, false); c[12] += _p[0]; c[13] += _p[1]; \
        _p = __builtin_amdgcn_cvt_pk_f32_fp8((int)(u4).w, true);  c[14] += _p[0]; c[15] += _p[1]; \
    } while (0)
    int e = beg;
    for (; e + 32 <= end; e += 32) {   // 32 edges: 2 idx loads, 2 gathers (32 rows in flight)
        int r0 = csr_row[e + q16];
        int r1 = csr_row[e + 16 + q16];
        uint4 u0 = H4[(size_t)r0 * 4 + lf16];
        uint4 u1 = H4[(size_t)r1 * 4 + lf16];
        ACCU4(u0);
        ACCU4(u1);
    }
    for (; e + 16 <= end; e += 16) {
        int r = csr_row[e + q16];
        uint4 u = H4[(size_t)r * 4 + lf16];
        ACCU4(u);
    }
    if (e + q16 < end) {  // masked tail (<16 edges)
        int r = csr_row[e + q16];
        uint4 u = H4[(size_t)r * 4 + lf16];
        ACCU4(u);
    }
    // reduce across the 16 edge-slots (lane bits 2..5)
#pragma unroll
    for (int i = 0; i < 16; ++i) {
        c[i] += __shfl_xor(c[i], 4);
        c[i] += __shfl_xor(c[i], 8);
        c[i] += __shfl_xor(c[i], 16);
        c[i] += __shfl_xor(c[i], 32);
    }
    {
        uint4 us = H4[(size_t)node * 4 + lf16];  // self loop (post-reduce, uniform)
        ACCU4(us);
    }
#undef ACCU4
    float dcn = dinv[node];
    // o computed in-place into c
#pragma unroll
    for (int i = 0; i < 4; ++i) {
        float4 z = *(const float4*)&h0[(size_t)node * 64 + lf16 * 16 + i * 4];
        c[4 * i + 0] = (1.0f - ALPHA) * (dcn * c[4 * i + 0]) + ALPHA * z.x;
        c[4 * i + 1] = (1.0f - ALPHA) * (dcn * c[4 * i + 1]) + ALPHA * z.y;
        c[4 * i + 2] = (1.0f - ALPHA) * (dcn * c[4 * i + 2]) + ALPHA * z.z;
        c[4 * i + 3] = (1.0f - ALPHA) * (dcn * c[4 * i + 3]) + ALPHA * z.w;
    }
    if (last) {
        // fused log_softmax: row spans the 4 lf16 lanes; xor {1,2} closed in quad
        float m = c[0];
#pragma unroll
        for (int i = 1; i < 16; ++i) m = fmaxf(m, c[i]);
        m = fmaxf(m, __shfl_xor(m, 1));
        m = fmaxf(m, __shfl_xor(m, 2));
        float s = 0.f;
#pragma unroll
        for (int i = 0; i < 16; ++i) s += expf(c[i] - m);
        s += __shfl_xor(s, 1);
        s += __shfl_xor(s, 2);
        float lg = logf(s);
        if (q16 == 0) {
#pragma unroll
            for (int i = 0; i < 4; ++i) {
                float4 o;
                o.x = c[4 * i + 0] - m - lg;
                o.y = c[4 * i + 1] - m - lg;
                o.z = c[4 * i + 2] - m - lg;
                o.w = c[4 * i + 3] - m - lg;
                *(float4*)&hfin[(size_t)node * 64 + lf16 * 16 + i * 4] = o;
            }
        }
    } else if (q16 == 0) {
        int p0 = __builtin_amdgcn_cvt_pk_fp8_f32(dcn * c[0], dcn * c[1], 0, false);
        p0 = __builtin_amdgcn_cvt_pk_fp8_f32(dcn * c[2], dcn * c[3], p0, true);
        int p1 = __builtin_amdgcn_cvt_pk_fp8_f32(dcn * c[4], dcn * c[5], 0, false);
        p1 = __builtin_amdgcn_cvt_pk_fp8_f32(dcn * c[6], dcn * c[7], p1, true);
        int p2 = __builtin_amdgcn_cvt_pk_fp8_f32(dcn * c[8], dcn * c[9], 0, false);
        p2 = __builtin_amdgcn_cvt_pk_fp8_f32(dcn * c[10], dcn * c[11], p2, true);
        int p3 = __builtin_amdgcn_cvt_pk_fp8_f32(dcn * c[12], dcn * c[13], 0, false);
        p3 = __builtin_amdgcn_cvt_pk_fp8_f32(dcn * c[14], dcn * c[15], p3, true);
        uint4 pk;
        pk.x = (unsigned)p0; pk.y = (unsigned)p1; pk.z = (unsigned)p2; pk.w = (unsigned)p3;
        ((uint4*)hs_out)[(size_t)node * 4 + lf16] = pk;
    }
}

extern "C" void kernel_launch(void* const* d_in, const int* in_sizes, int n_in,
                              void* d_out, int out_size, void* d_ws, size_t ws_size,
                              hipStream_t stream) {
    const float* x  = (const float*)d_in[0];
    const int*   ei = (const int*)d_in[1];
    const float* W1 = (const float*)d_in[2];
    const float* b1 = (const float*)d_in[3];
    const float* W2 = (const float*)d_in[4];
    const float* b2 = (const float*)d_in[5];
    float* out = (float*)d_out;
    int N = in_sizes[0] / IN_DIM;
    int E = in_sizes[1] / 2;
    int nbkt = (N + 511) >> BKT_SHIFT;

    char* ws = (char*)d_ws;
    size_t off = 0;
    auto alloc = [&](size_t bytes) -> void* {
        void* p = ws + off;
        off += (bytes + 255) & ~(size_t)255;
        return p;
    };
    float* h0     = (float*)alloc((size_t)N * OUT_DIM * 4);
    float* dinv   = (float*)alloc((size_t)N * 4);
    int*   indptr = (int*)alloc((size_t)(N + 1) * 4);
    int*   bcnt   = (int*)alloc(256 * 4);
    int*   bbase  = (int*)alloc(256 * 4);
    int*   bfill  = (int*)alloc(256 * 4);
    int*   packed = (int*)alloc((size_t)E * 4);
    int*   csr_row= (int*)alloc((size_t)E * 4);
    unsigned short* w1p = (unsigned short*)alloc((size_t)IN_DIM * HID_DIM * 2);
    unsigned short* w2p = (unsigned short*)alloc((size_t)HID_DIM * OUT_DIM * 2);
    unsigned char* hsA = (unsigned char*)alloc((size_t)N * OUT_DIM);  // fp8
    unsigned char* hsB = (unsigned char*)alloc((size_t)N * OUT_DIM);  // fp8
    (void)ws_size; (void)n_in; (void)out_size;

    hipMemsetAsync(bcnt, 0, 256 * 4, stream);

    prep_w1_kernel<<<(IN_DIM * HID_DIM) / 256, 256, 0, stream>>>(W1, w1p);
    prep_w2_kernel<<<(HID_DIM * OUT_DIM) / 256, 256, 0, stream>>>(W2, w2p);

    int pgrid = (E + PART_EPB - 1) / PART_EPB;
    bucket_count_kernel<<<pgrid, 256, 0, stream>>>(ei, E, bcnt);
    bucket_scan_kernel<<<1, 256, 0, stream>>>(bcnt, bbase, bfill, indptr, E, N);
    partition_kernel<<<pgrid, 256, 0, stream>>>(ei, E, bfill, packed);
    fine_kernel<<<nbkt, 256, 0, stream>>>(packed, bbase, bcnt, csr_row, indptr, dinv, N);

    mlp_mfma_kernel<<<(N + 63) / 64, 256, 0, stream>>>(x, w1p, b1, w2p, b2, dinv,
                                                       h0, hsA, N);

    int pb = (N + 3) / 4;
    for (int it = 0; it < KPROP; ++it) {
        const unsigned char* hin = (it % 2 == 0) ? hsA : hsB;
        unsigned char* hout = (it % 2 == 0) ? hsB : hsA;
        int last = (it == KPROP - 1) ? 1 : 0;
        prop_fp8_kernel<<<pb, 256, 0, stream>>>(hin, h0, dinv, csr_row, indptr,
                                                hout, out, last, N);
    }
}

// Round 21
// 459.778 us; speedup vs baseline: 1.2019x; 1.2019x over previous
//
#include <hip/hip_runtime.h>

#define IN_DIM  512
#define HID_DIM 256
#define OUT_DIM 64
#define KPROP   5
#define ALPHA   0.1f

#define BKT_SHIFT 9            // 512 dst nodes per bucket
#define PART_EPB  8192         // edges per partition block

typedef short short8v __attribute__((ext_vector_type(8)));
typedef float f32x4   __attribute__((ext_vector_type(4)));
typedef float f32x2   __attribute__((ext_vector_type(2)));

__device__ __forceinline__ unsigned short f2bf(float f) {
    unsigned u = __builtin_bit_cast(unsigned, f);
    unsigned r = (u + 0x7FFFu + ((u >> 16) & 1u)) >> 16;
    return (unsigned short)r;
}

// ---------------- bucket-level edge count ----------------
__global__ __launch_bounds__(256) void bucket_count_kernel(const int* __restrict__ ei, int E,
                                                           int* __restrict__ bucketCnt) {
    __shared__ int hist[256];
    int t = threadIdx.x;
    hist[t] = 0;
    __syncthreads();
    int e0 = blockIdx.x * PART_EPB;
#pragma unroll 4
    for (int i = 0; i < PART_EPB / 256; ++i) {
        int e = e0 + i * 256 + t;
        if (e < E) atomicAdd(&hist[ei[E + e] >> BKT_SHIFT], 1);
    }
    __syncthreads();
    if (hist[t] > 0) atomicAdd(&bucketCnt[t], hist[t]);
}

// ---------------- bucket scan (1 block) ----------------
__global__ __launch_bounds__(256) void bucket_scan_kernel(const int* __restrict__ bucketCnt,
                                                          int* __restrict__ bucketBase,
                                                          int* __restrict__ bucketFill,
                                                          int* __restrict__ indptr,
                                                          int E, int N) {
    __shared__ int sm[256];
    int t = threadIdx.x;
    int v = bucketCnt[t];
    sm[t] = v;
    __syncthreads();
    for (int off = 1; off < 256; off <<= 1) {
        int add = 0;
        if (t >= off) add = sm[t - off];
        __syncthreads();
        if (t >= off) sm[t] += add;
        __syncthreads();
    }
    int base = sm[t] - v;
    bucketBase[t] = base;
    bucketFill[t] = base;
    if (t == 0) indptr[N] = E;
}

// ---------------- partition; packed = (dst&511)<<17 | src ----------------
__global__ __launch_bounds__(256) void partition_kernel(const int* __restrict__ ei, int E,
                                                        int* __restrict__ bucketFill,
                                                        int* __restrict__ packed) {
    __shared__ int hist[256];
    __shared__ int base[256];
    int t = threadIdx.x;
    int e0 = blockIdx.x * PART_EPB;
    hist[t] = 0;
    __syncthreads();
#pragma unroll 4
    for (int i = 0; i < PART_EPB / 256; ++i) {
        int e = e0 + i * 256 + t;
        if (e < E) atomicAdd(&hist[ei[E + e] >> BKT_SHIFT], 1);
    }
    __syncthreads();
    int cnt = hist[t];
    if (cnt > 0) base[t] = atomicAdd(&bucketFill[t], cnt);
    __syncthreads();
#pragma unroll 4
    for (int i = 0; i < PART_EPB / 256; ++i) {
        int e = e0 + i * 256 + t;
        if (e < E) {
            int dst = ei[E + e];
            int src = ei[e];
            int b = dst >> BKT_SHIFT;
            int pos = atomicAdd(&base[b], 1);
            packed[pos] = ((dst & 511) << 17) | src;
        }
    }
}

// ---------------- fused per-bucket: node hist + indptr + dinv + scatter ----------------
__global__ __launch_bounds__(256) void fine_kernel(const int* __restrict__ packed,
                                                   const int* __restrict__ bucketBase,
                                                   const int* __restrict__ bucketCnt,
                                                   int* __restrict__ csr_row,
                                                   int* __restrict__ indptr,
                                                   float* __restrict__ dinv, int N) {
    __shared__ int cnt[512];
    __shared__ int pre[512];
    __shared__ int fill[512];
    __shared__ int sm[256];
    int b = blockIdx.x;
    int t = threadIdx.x;
    int d0 = b << BKT_SHIFT;
    int nd = N - d0;
    if (nd > 512) nd = 512;
    cnt[t] = 0; cnt[t + 256] = 0;
    fill[t] = 0; fill[t + 256] = 0;
    __syncthreads();
    int beg = bucketBase[b];
    int end = beg + bucketCnt[b];
    for (int e = beg + t; e < end; e += 256)
        atomicAdd(&cnt[((unsigned)packed[e]) >> 17], 1);
    __syncthreads();
    int c0 = cnt[2 * t], c1 = cnt[2 * t + 1];
    int s = c0 + c1;
    sm[t] = s;
    __syncthreads();
    for (int off = 1; off < 256; off <<= 1) {
        int add = 0;
        if (t >= off) add = sm[t - off];
        __syncthreads();
        if (t >= off) sm[t] += add;
        __syncthreads();
    }
    int ex = sm[t] - s;
    pre[2 * t] = ex;
    pre[2 * t + 1] = ex + c0;
    __syncthreads();
    for (int dl = t; dl < nd; dl += 256) {
        indptr[d0 + dl] = beg + pre[dl];
        dinv[d0 + dl] = rsqrtf((float)(cnt[dl] + 1));
    }
    for (int e = beg + t; e < end; e += 256) {
        unsigned p = (unsigned)packed[e];
        int dl = (int)(p >> 17);
        int src = (int)(p & 0x1FFFFu);
        int pos = beg + pre[dl] + atomicAdd(&fill[dl], 1);
        csr_row[pos] = src;
    }
}

// ---------------- weight prep ----------------
__global__ __launch_bounds__(256) void prep_w1_kernel(const float* __restrict__ W1,
                                                      unsigned short* __restrict__ w1p) {
    int idx = blockIdx.x * 256 + threadIdx.x;
    int q = idx >> 14;
    int rem = idx & 16383;
    int c = rem >> 6, j = rem & 63;
    w1p[idx] = f2bf(W1[(size_t)(q * 64 + j) * HID_DIM + c]);
}

__global__ __launch_bounds__(256) void prep_w2_kernel(const float* __restrict__ W2,
                                                      unsigned short* __restrict__ w2p) {
    int idx = blockIdx.x * 256 + threadIdx.x;
    int c = idx >> 8, k = idx & 255;
    w2p[idx] = f2bf(W2[(size_t)k * OUT_DIM + c]);
}

// ---------------- MFMA MLP: r16 structure; epilogue writes fp8 hs ----------------
struct __align__(16) MlpSmem {
    union {
        struct {
            unsigned short xs[64][72];     // 9216 B
            unsigned short ws[256][72];    // 36864 B
        } p1;
        struct {
            unsigned short hid[64][264];   // 33792 B
            unsigned short w2s[32][264];   // 16896 B
        } p2;                              // 50688 B LDS -> 3 blocks/CU
    };
};

__device__ __forceinline__ float4 ldx1(const float* __restrict__ x, int row0, int N,
                                       int t, int i, int q) {
    int e = t * 4 + i * 1024;
    int r = e >> 6, j = e & 63;
    if (row0 + r < N) return *(const float4*)&x[(size_t)(row0 + r) * IN_DIM + q * 64 + j];
    return make_float4(0.f, 0.f, 0.f, 0.f);
}

__global__ __launch_bounds__(256, 3) void mlp_mfma_kernel(const float* __restrict__ x,
                                                          const unsigned short* __restrict__ w1p,
                                                          const float* __restrict__ b1,
                                                          const unsigned short* __restrict__ w2p,
                                                          const float* __restrict__ b2,
                                                          const float* __restrict__ dinv,
                                                          float* __restrict__ h0,
                                                          unsigned char* __restrict__ hs,
                                                          int N) {
    __shared__ MlpSmem sm;
    int t = threadIdx.x;
    int w = t >> 6, l = t & 63;
    int l15 = l & 15, l4 = l >> 4;
    int wr0 = w * 16;
    int row0 = blockIdx.x * 64;

    f32x4 acc[16];
#pragma unroll
    for (int i = 0; i < 16; ++i) acc[i] = (f32x4){0.f, 0.f, 0.f, 0.f};

    float4 xr0, xr1, xr2, xr3;
    uint4 wv0, wv1, wv2, wv3, wv4, wv5, wv6, wv7;

#define LOADX(q) do { \
        xr0 = ldx1(x, row0, N, t, 0, (q)); \
        xr1 = ldx1(x, row0, N, t, 1, (q)); \
        xr2 = ldx1(x, row0, N, t, 2, (q)); \
        xr3 = ldx1(x, row0, N, t, 3, (q)); \
    } while (0)
#define LOADW(q) do { \
        const unsigned short* _s = w1p + (q) * 16384; \
        wv0 = *(const uint4*)&_s[t * 8 + 0 * 2048]; \
        wv1 = *(const uint4*)&_s[t * 8 + 1 * 2048]; \
        wv2 = *(const uint4*)&_s[t * 8 + 2 * 2048]; \
        wv3 = *(const uint4*)&_s[t * 8 + 3 * 2048]; \
        wv4 = *(const uint4*)&_s[t * 8 + 4 * 2048]; \
        wv5 = *(const uint4*)&_s[t * 8 + 5 * 2048]; \
        wv6 = *(const uint4*)&_s[t * 8 + 6 * 2048]; \
        wv7 = *(const uint4*)&_s[t * 8 + 7 * 2048]; \
    } while (0)
#define STX(i, v) do { \
        int e = t * 4 + (i) * 1024; \
        int r = e >> 6, j = e & 63; \
        unsigned u0 = (unsigned)f2bf((v).x) | ((unsigned)f2bf((v).y) << 16); \
        unsigned u1 = (unsigned)f2bf((v).z) | ((unsigned)f2bf((v).w) << 16); \
        *(uint2*)&sm.p1.xs[r][j] = make_uint2(u0, u1); \
    } while (0)
#define STW(i, v) do { \
        int e = t * 8 + (i) * 2048; \
        int c = e >> 6, j = e & 63; \
        *(uint4*)&sm.p1.ws[c][j] = (v); \
    } while (0)

    LOADX(0);
    LOADW(0);

    for (int q = 0; q < 8; ++q) {
        __syncthreads();
        STX(0, xr0); STX(1, xr1); STX(2, xr2); STX(3, xr3);
        STW(0, wv0); STW(1, wv1); STW(2, wv2); STW(3, wv3);
        STW(4, wv4); STW(5, wv5); STW(6, wv6); STW(7, wv7);
        __syncthreads();
        if (q < 7) {
            LOADX(q + 1);
            LOADW(q + 1);
        }
#pragma unroll
        for (int s = 0; s < 2; ++s) {
            short8v a = *(const short8v*)&sm.p1.xs[wr0 + l15][s * 32 + l4 * 8];
#pragma unroll
            for (int tc = 0; tc < 16; ++tc) {
                short8v b = *(const short8v*)&sm.p1.ws[tc * 16 + l15][s * 32 + l4 * 8];
                acc[tc] = __builtin_amdgcn_mfma_f32_16x16x32_bf16(a, b, acc[tc], 0, 0, 0);
            }
        }
    }
    __syncthreads();  // xs/ws dead; p2 overlay begins

#pragma unroll
    for (int tc = 0; tc < 16; ++tc) {
        float bv = b1[tc * 16 + l15];
#pragma unroll
        for (int i = 0; i < 4; ++i) {
            float v = fmaxf(acc[tc][i] + bv, 0.f);
            sm.p2.hid[wr0 + l4 * 4 + i][tc * 16 + l15] = f2bf(v);
        }
    }

    f32x4 acc2[4];
#pragma unroll
    for (int i = 0; i < 4; ++i) acc2[i] = (f32x4){0.f, 0.f, 0.f, 0.f};

#pragma unroll
    for (int hf = 0; hf < 2; ++hf) {
#pragma unroll
        for (int i = 0; i < 4; ++i) {
            int e = t * 8 + i * 2048;
            int c = e >> 8, k = e & 255;
            *(uint4*)&sm.p2.w2s[c][k] = *(const uint4*)&w2p[hf * 8192 + e];
        }
        __syncthreads();
#pragma unroll
        for (int s = 0; s < 8; ++s) {
            short8v a = *(const short8v*)&sm.p2.hid[wr0 + l15][s * 32 + l4 * 8];
#pragma unroll
            for (int tcl = 0; tcl < 2; ++tcl) {
                short8v b = *(const short8v*)&sm.p2.w2s[tcl * 16 + l15][s * 32 + l4 * 8];
                acc2[hf * 2 + tcl] =
                    __builtin_amdgcn_mfma_f32_16x16x32_bf16(a, b, acc2[hf * 2 + tcl], 0, 0, 0);
            }
        }
        __syncthreads();
    }

    // epilogue2: h0 (fp32) + hs = fp8_e4m3(dinv * h0)
#pragma unroll
    for (int i = 0; i < 4; ++i) {
        int row = row0 + wr0 + l4 * 4 + i;
        if (row < N) {
            float dv = dinv[row];
#pragma unroll
            for (int tc = 0; tc < 4; ++tc) {
                float v = acc2[tc][i] + b2[tc * 16 + l15];
                h0[(size_t)row * OUT_DIM + tc * 16 + l15] = v;
                float sv = dv * v;
                int pk = __builtin_amdgcn_cvt_pk_fp8_f32(sv, sv, 0, false);
                hs[(size_t)row * OUT_DIM + tc * 16 + l15] = (unsigned char)(pk & 0xFF);
            }
        }
    }
#undef LOADX
#undef LOADW
#undef STX
#undef STW
}

// ---------------- propagation, fp8 rows, 8-lane/row layout (8 rows per gather instr) ----
// r18 lesson: mega-trips (more rows in flight) pay. Widen: lane = (q8 = l>>3
// edge-slot, lf8 = l&7 feature-octet); each lane loads uint2 (8 fp8) -> one
// gather instruction covers 8 rows; 32-edge trip = 4 gathers, 32 rows in flight.
// r20 lesson: 16B/lane (4-lane/row) REGRESSES — serial decode chain + shfl
// explosion + VGPR growth; 8B/lane is the sweet spot.
__global__ __launch_bounds__(256) void prop_fp8_kernel(const unsigned char* __restrict__ hs,
                                                       const float* __restrict__ h0,
                                                       const float* __restrict__ dinv,
                                                       const int* __restrict__ csr_row,
                                                       const int* __restrict__ indptr,
                                                       unsigned char* __restrict__ hs_out,
                                                       float* __restrict__ hfin,
                                                       int last, int N) {
    int node = blockIdx.x * 4 + (threadIdx.x >> 6);
    if (node >= N) return;
    int l = threadIdx.x & 63;
    int q8 = l >> 3, lf8 = l & 7;
    const uint2* H2 = (const uint2*)hs;   // [N][8] uint2
    int beg = indptr[node], end = indptr[node + 1];
    float b0 = 0.f, b1v = 0.f, b2v = 0.f, b3 = 0.f;
    float b4 = 0.f, b5 = 0.f, b6 = 0.f, b7 = 0.f;
#define ACCU2(u2) do { \
        f32x2 _p0 = __builtin_amdgcn_cvt_pk_f32_fp8((int)(u2).x, false); \
        f32x2 _p1 = __builtin_amdgcn_cvt_pk_f32_fp8((int)(u2).x, true);  \
        f32x2 _p2 = __builtin_amdgcn_cvt_pk_f32_fp8((int)(u2).y, false); \
        f32x2 _p3 = __builtin_amdgcn_cvt_pk_f32_fp8((int)(u2).y, true);  \
        b0 += _p0[0]; b1v += _p0[1]; b2v += _p1[0]; b3 += _p1[1];        \
        b4 += _p2[0]; b5 += _p2[1]; b6 += _p3[0]; b7 += _p3[1];          \
    } while (0)
    int e = beg;
    for (; e + 32 <= end; e += 32) {   // 32 edges: 4 idx loads, 4 gathers (32 rows in flight)
        int r0 = csr_row[e + 0 + q8];
        int r1 = csr_row[e + 8 + q8];
        int r2 = csr_row[e + 16 + q8];
        int r3 = csr_row[e + 24 + q8];
        uint2 u0 = H2[(size_t)r0 * 8 + lf8];
        uint2 u1 = H2[(size_t)r1 * 8 + lf8];
        uint2 u2 = H2[(size_t)r2 * 8 + lf8];
        uint2 u3 = H2[(size_t)r3 * 8 + lf8];
        ACCU2(u0); ACCU2(u1); ACCU2(u2); ACCU2(u3);
    }
    for (; e + 8 <= end; e += 8) {
        int r = csr_row[e + q8];
        uint2 u = H2[(size_t)r * 8 + lf8];
        ACCU2(u);
    }
    if (e + q8 < end) {  // masked tail (<8 edges)
        int r = csr_row[e + q8];
        uint2 u = H2[(size_t)r * 8 + lf8];
        ACCU2(u);
    }
    // reduce across the 8 edge-slots (lane bits 3,4,5)
    b0 += __shfl_xor(b0, 8);  b1v += __shfl_xor(b1v, 8);
    b2v += __shfl_xor(b2v, 8); b3 += __shfl_xor(b3, 8);
    b4 += __shfl_xor(b4, 8);  b5 += __shfl_xor(b5, 8);
    b6 += __shfl_xor(b6, 8);  b7 += __shfl_xor(b7, 8);
    b0 += __shfl_xor(b0, 16); b1v += __shfl_xor(b1v, 16);
    b2v += __shfl_xor(b2v, 16); b3 += __shfl_xor(b3, 16);
    b4 += __shfl_xor(b4, 16); b5 += __shfl_xor(b5, 16);
    b6 += __shfl_xor(b6, 16); b7 += __shfl_xor(b7, 16);
    b0 += __shfl_xor(b0, 32); b1v += __shfl_xor(b1v, 32);
    b2v += __shfl_xor(b2v, 32); b3 += __shfl_xor(b3, 32);
    b4 += __shfl_xor(b4, 32); b5 += __shfl_xor(b5, 32);
    b6 += __shfl_xor(b6, 32); b7 += __shfl_xor(b7, 32);
    {
        uint2 us = H2[(size_t)node * 8 + lf8];  // self loop (post-reduce, uniform)
        ACCU2(us);
    }
#undef ACCU2
    float dcn = dinv[node];
    float4 za = *(const float4*)&h0[(size_t)node * 64 + lf8 * 8];
    float4 zb = *(const float4*)&h0[(size_t)node * 64 + lf8 * 8 + 4];
    float o0 = (1.0f - ALPHA) * (dcn * b0) + ALPHA * za.x;
    float o1 = (1.0f - ALPHA) * (dcn * b1v) + ALPHA * za.y;
    float o2 = (1.0f - ALPHA) * (dcn * b2v) + ALPHA * za.z;
    float o3 = (1.0f - ALPHA) * (dcn * b3) + ALPHA * za.w;
    float o4 = (1.0f - ALPHA) * (dcn * b4) + ALPHA * zb.x;
    float o5 = (1.0f - ALPHA) * (dcn * b5) + ALPHA * zb.y;
    float o6 = (1.0f - ALPHA) * (dcn * b6) + ALPHA * zb.z;
    float o7 = (1.0f - ALPHA) * (dcn * b7) + ALPHA * zb.w;
    if (last) {
        // fused log_softmax: row lives in the 8 lf8 lanes of slot q8==0;
        // xor {1,2,4} is closed within each 8-lane group.
        float m = fmaxf(fmaxf(fmaxf(o0, o1), fmaxf(o2, o3)),
                        fmaxf(fmaxf(o4, o5), fmaxf(o6, o7)));
        m = fmaxf(m, __shfl_xor(m, 1));
        m = fmaxf(m, __shfl_xor(m, 2));
        m = fmaxf(m, __shfl_xor(m, 4));
        float s = expf(o0 - m) + expf(o1 - m) + expf(o2 - m) + expf(o3 - m) +
                  expf(o4 - m) + expf(o5 - m) + expf(o6 - m) + expf(o7 - m);
        s += __shfl_xor(s, 1);
        s += __shfl_xor(s, 2);
        s += __shfl_xor(s, 4);
        float lg = logf(s);
        if (q8 == 0) {
            float4 oa, ob;
            oa.x = o0 - m - lg; oa.y = o1 - m - lg; oa.z = o2 - m - lg; oa.w = o3 - m - lg;
            ob.x = o4 - m - lg; ob.y = o5 - m - lg; ob.z = o6 - m - lg; ob.w = o7 - m - lg;
            *(float4*)&hfin[(size_t)node * 64 + lf8 * 8] = oa;
            *(float4*)&hfin[(size_t)node * 64 + lf8 * 8 + 4] = ob;
        }
    } else if (q8 == 0) {
        int pk0 = __builtin_amdgcn_cvt_pk_fp8_f32(dcn * o0, dcn * o1, 0, false);
        pk0 = __builtin_amdgcn_cvt_pk_fp8_f32(dcn * o2, dcn * o3, pk0, true);
        int pk1 = __builtin_amdgcn_cvt_pk_fp8_f32(dcn * o4, dcn * o5, 0, false);
        pk1 = __builtin_amdgcn_cvt_pk_fp8_f32(dcn * o6, dcn * o7, pk1, true);
        ((uint2*)hs_out)[(size_t)node * 8 + lf8] = make_uint2((unsigned)pk0, (unsigned)pk1);
    }
}

extern "C" void kernel_launch(void* const* d_in, const int* in_sizes, int n_in,
                              void* d_out, int out_size, void* d_ws, size_t ws_size,
                              hipStream_t stream) {
    const float* x  = (const float*)d_in[0];
    const int*   ei = (const int*)d_in[1];
    const float* W1 = (const float*)d_in[2];
    const float* b1 = (const float*)d_in[3];
    const float* W2 = (const float*)d_in[4];
    const float* b2 = (const float*)d_in[5];
    float* out = (float*)d_out;
    int N = in_sizes[0] / IN_DIM;
    int E = in_sizes[1] / 2;
    int nbkt = (N + 511) >> BKT_SHIFT;

    char* ws = (char*)d_ws;
    size_t off = 0;
    auto alloc = [&](size_t bytes) -> void* {
        void* p = ws + off;
        off += (bytes + 255) & ~(size_t)255;
        return p;
    };
    float* h0     = (float*)alloc((size_t)N * OUT_DIM * 4);
    float* dinv   = (float*)alloc((size_t)N * 4);
    int*   indptr = (int*)alloc((size_t)(N + 1) * 4);
    int*   bcnt   = (int*)alloc(256 * 4);
    int*   bbase  = (int*)alloc(256 * 4);
    int*   bfill  = (int*)alloc(256 * 4);
    int*   packed = (int*)alloc((size_t)E * 4);
    int*   csr_row= (int*)alloc((size_t)E * 4);
    unsigned short* w1p = (unsigned short*)alloc((size_t)IN_DIM * HID_DIM * 2);
    unsigned short* w2p = (unsigned short*)alloc((size_t)HID_DIM * OUT_DIM * 2);
    unsigned char* hsA = (unsigned char*)alloc((size_t)N * OUT_DIM);  // fp8
    unsigned char* hsB = (unsigned char*)alloc((size_t)N * OUT_DIM);  // fp8
    (void)ws_size; (void)n_in; (void)out_size;

    hipMemsetAsync(bcnt, 0, 256 * 4, stream);

    prep_w1_kernel<<<(IN_DIM * HID_DIM) / 256, 256, 0, stream>>>(W1, w1p);
    prep_w2_kernel<<<(HID_DIM * OUT_DIM) / 256, 256, 0, stream>>>(W2, w2p);

    int pgrid = (E + PART_EPB - 1) / PART_EPB;
    bucket_count_kernel<<<pgrid, 256, 0, stream>>>(ei, E, bcnt);
    bucket_scan_kernel<<<1, 256, 0, stream>>>(bcnt, bbase, bfill, indptr, E, N);
    partition_kernel<<<pgrid, 256, 0, stream>>>(ei, E, bfill, packed);
    fine_kernel<<<nbkt, 256, 0, stream>>>(packed, bbase, bcnt, csr_row, indptr, dinv, N);

    mlp_mfma_kernel<<<(N + 63) / 64, 256, 0, stream>>>(x, w1p, b1, w2p, b2, dinv,
                                                       h0, hsA, N);

    int pb = (N + 3) / 4;
    for (int it = 0; it < KPROP; ++it) {
        const unsigned char* hin = (it % 2 == 0) ? hsA : hsB;
        unsigned char* hout = (it % 2 == 0) ? hsB : hsA;
        int last = (it == KPROP - 1) ? 1 : 0;
        prop_fp8_kernel<<<pb, 256, 0, stream>>>(hin, h0, dinv, csr_row, indptr,
                                                hout, out, last, N);
    }
}

// Round 22
// 457.176 us; speedup vs baseline: 1.2087x; 1.0057x over previous
//
#include <hip/hip_runtime.h>

#define IN_DIM  512
#define HID_DIM 256
#define OUT_DIM 64
#define KPROP   5
#define ALPHA   0.1f

#define BKT_SHIFT 9            // 512 dst nodes per bucket
#define PART_EPB  8192         // edges per partition block

typedef short short8v __attribute__((ext_vector_type(8)));
typedef float f32x4   __attribute__((ext_vector_type(4)));
typedef float f32x2   __attribute__((ext_vector_type(2)));

__device__ __forceinline__ unsigned short f2bf(float f) {
    unsigned u = __builtin_bit_cast(unsigned, f);
    unsigned r = (u + 0x7FFFu + ((u >> 16) & 1u)) >> 16;
    return (unsigned short)r;
}
__device__ __forceinline__ float bflo(unsigned v) { return __builtin_bit_cast(float, v << 16); }
__device__ __forceinline__ float bfhi(unsigned v) { return __builtin_bit_cast(float, v & 0xffff0000u); }

// ---------------- bucket-level edge count ----------------
__global__ __launch_bounds__(256) void bucket_count_kernel(const int* __restrict__ ei, int E,
                                                           int* __restrict__ bucketCnt) {
    __shared__ int hist[256];
    int t = threadIdx.x;
    hist[t] = 0;
    __syncthreads();
    int e0 = blockIdx.x * PART_EPB;
#pragma unroll 4
    for (int i = 0; i < PART_EPB / 256; ++i) {
        int e = e0 + i * 256 + t;
        if (e < E) atomicAdd(&hist[ei[E + e] >> BKT_SHIFT], 1);
    }
    __syncthreads();
    if (hist[t] > 0) atomicAdd(&bucketCnt[t], hist[t]);
}

// ---------------- bucket scan (1 block) ----------------
__global__ __launch_bounds__(256) void bucket_scan_kernel(const int* __restrict__ bucketCnt,
                                                          int* __restrict__ bucketBase,
                                                          int* __restrict__ bucketFill,
                                                          int* __restrict__ indptr,
                                                          int E, int N) {
    __shared__ int sm[256];
    int t = threadIdx.x;
    int v = bucketCnt[t];
    sm[t] = v;
    __syncthreads();
    for (int off = 1; off < 256; off <<= 1) {
        int add = 0;
        if (t >= off) add = sm[t - off];
        __syncthreads();
        if (t >= off) sm[t] += add;
        __syncthreads();
    }
    int base = sm[t] - v;
    bucketBase[t] = base;
    bucketFill[t] = base;
    if (t == 0) indptr[N] = E;
}

// ---------------- partition; packed = (dst&511)<<17 | src ----------------
__global__ __launch_bounds__(256) void partition_kernel(const int* __restrict__ ei, int E,
                                                        int* __restrict__ bucketFill,
                                                        int* __restrict__ packed) {
    __shared__ int hist[256];
    __shared__ int base[256];
    int t = threadIdx.x;
    int e0 = blockIdx.x * PART_EPB;
    hist[t] = 0;
    __syncthreads();
#pragma unroll 4
    for (int i = 0; i < PART_EPB / 256; ++i) {
        int e = e0 + i * 256 + t;
        if (e < E) atomicAdd(&hist[ei[E + e] >> BKT_SHIFT], 1);
    }
    __syncthreads();
    int cnt = hist[t];
    if (cnt > 0) base[t] = atomicAdd(&bucketFill[t], cnt);
    __syncthreads();
#pragma unroll 4
    for (int i = 0; i < PART_EPB / 256; ++i) {
        int e = e0 + i * 256 + t;
        if (e < E) {
            int dst = ei[E + e];
            int src = ei[e];
            int b = dst >> BKT_SHIFT;
            int pos = atomicAdd(&base[b], 1);
            packed[pos] = ((dst & 511) << 17) | src;
        }
    }
}

// ---------------- fused per-bucket: node hist + indptr + dinv + scatter ----------------
__global__ __launch_bounds__(256) void fine_kernel(const int* __restrict__ packed,
                                                   const int* __restrict__ bucketBase,
                                                   const int* __restrict__ bucketCnt,
                                                   int* __restrict__ csr_row,
                                                   int* __restrict__ indptr,
                                                   float* __restrict__ dinv, int N) {
    __shared__ int cnt[512];
    __shared__ int pre[512];
    __shared__ int fill[512];
    __shared__ int sm[256];
    int b = blockIdx.x;
    int t = threadIdx.x;
    int d0 = b << BKT_SHIFT;
    int nd = N - d0;
    if (nd > 512) nd = 512;
    cnt[t] = 0; cnt[t + 256] = 0;
    fill[t] = 0; fill[t + 256] = 0;
    __syncthreads();
    int beg = bucketBase[b];
    int end = beg + bucketCnt[b];
    for (int e = beg + t; e < end; e += 256)
        atomicAdd(&cnt[((unsigned)packed[e]) >> 17], 1);
    __syncthreads();
    int c0 = cnt[2 * t], c1 = cnt[2 * t + 1];
    int s = c0 + c1;
    sm[t] = s;
    __syncthreads();
    for (int off = 1; off < 256; off <<= 1) {
        int add = 0;
        if (t >= off) add = sm[t - off];
        __syncthreads();
        if (t >= off) sm[t] += add;
        __syncthreads();
    }
    int ex = sm[t] - s;
    pre[2 * t] = ex;
    pre[2 * t + 1] = ex + c0;
    __syncthreads();
    for (int dl = t; dl < nd; dl += 256) {
        indptr[d0 + dl] = beg + pre[dl];
        dinv[d0 + dl] = rsqrtf((float)(cnt[dl] + 1));
    }
    for (int e = beg + t; e < end; e += 256) {
        unsigned p = (unsigned)packed[e];
        int dl = (int)(p >> 17);
        int src = (int)(p & 0x1FFFFu);
        int pos = beg + pre[dl] + atomicAdd(&fill[dl], 1);
        csr_row[pos] = src;
    }
}

// ---------------- weight prep ----------------
__global__ __launch_bounds__(256) void prep_w1_kernel(const float* __restrict__ W1,
                                                      unsigned short* __restrict__ w1p) {
    int idx = blockIdx.x * 256 + threadIdx.x;
    int q = idx >> 14;
    int rem = idx & 16383;
    int c = rem >> 6, j = rem & 63;
    w1p[idx] = f2bf(W1[(size_t)(q * 64 + j) * HID_DIM + c]);
}

__global__ __launch_bounds__(256) void prep_w2_kernel(const float* __restrict__ W2,
                                                      unsigned short* __restrict__ w2p) {
    int idx = blockIdx.x * 256 + threadIdx.x;
    int c = idx >> 8, k = idx & 255;
    w2p[idx] = f2bf(W2[(size_t)k * OUT_DIM + c]);
}

// ---------------- MFMA MLP: r16 structure; epilogue writes zb16 (ALPHA-folded) + fp8 hs ----
// r22 change: h0 fp32 stream eliminated. zb = bf16(ALPHA*(xW+b)) is the only
// alpha-term consumer; prop reads it as 8xbf16/lane.
struct __align__(16) MlpSmem {
    union {
        struct {
            unsigned short xs[64][72];     // 9216 B
            unsigned short ws[256][72];    // 36864 B
        } p1;
        struct {
            unsigned short hid[64][264];   // 33792 B
            unsigned short w2s[32][264];   // 16896 B
        } p2;                              // 50688 B LDS -> 3 blocks/CU
    };
};

__device__ __forceinline__ float4 ldx1(const float* __restrict__ x, int row0, int N,
                                       int t, int i, int q) {
    int e = t * 4 + i * 1024;
    int r = e >> 6, j = e & 63;
    if (row0 + r < N) return *(const float4*)&x[(size_t)(row0 + r) * IN_DIM + q * 64 + j];
    return make_float4(0.f, 0.f, 0.f, 0.f);
}

__global__ __launch_bounds__(256, 3) void mlp_mfma_kernel(const float* __restrict__ x,
                                                          const unsigned short* __restrict__ w1p,
                                                          const float* __restrict__ b1,
                                                          const unsigned short* __restrict__ w2p,
                                                          const float* __restrict__ b2,
                                                          const float* __restrict__ dinv,
                                                          unsigned short* __restrict__ zb,
                                                          unsigned char* __restrict__ hs,
                                                          int N) {
    __shared__ MlpSmem sm;
    int t = threadIdx.x;
    int w = t >> 6, l = t & 63;
    int l15 = l & 15, l4 = l >> 4;
    int wr0 = w * 16;
    int row0 = blockIdx.x * 64;

    f32x4 acc[16];
#pragma unroll
    for (int i = 0; i < 16; ++i) acc[i] = (f32x4){0.f, 0.f, 0.f, 0.f};

    float4 xr0, xr1, xr2, xr3;
    uint4 wv0, wv1, wv2, wv3, wv4, wv5, wv6, wv7;

#define LOADX(q) do { \
        xr0 = ldx1(x, row0, N, t, 0, (q)); \
        xr1 = ldx1(x, row0, N, t, 1, (q)); \
        xr2 = ldx1(x, row0, N, t, 2, (q)); \
        xr3 = ldx1(x, row0, N, t, 3, (q)); \
    } while (0)
#define LOADW(q) do { \
        const unsigned short* _s = w1p + (q) * 16384; \
        wv0 = *(const uint4*)&_s[t * 8 + 0 * 2048]; \
        wv1 = *(const uint4*)&_s[t * 8 + 1 * 2048]; \
        wv2 = *(const uint4*)&_s[t * 8 + 2 * 2048]; \
        wv3 = *(const uint4*)&_s[t * 8 + 3 * 2048]; \
        wv4 = *(const uint4*)&_s[t * 8 + 4 * 2048]; \
        wv5 = *(const uint4*)&_s[t * 8 + 5 * 2048]; \
        wv6 = *(const uint4*)&_s[t * 8 + 6 * 2048]; \
        wv7 = *(const uint4*)&_s[t * 8 + 7 * 2048]; \
    } while (0)
#define STX(i, v) do { \
        int e = t * 4 + (i) * 1024; \
        int r = e >> 6, j = e & 63; \
        unsigned u0 = (unsigned)f2bf((v).x) | ((unsigned)f2bf((v).y) << 16); \
        unsigned u1 = (unsigned)f2bf((v).z) | ((unsigned)f2bf((v).w) << 16); \
        *(uint2*)&sm.p1.xs[r][j] = make_uint2(u0, u1); \
    } while (0)
#define STW(i, v) do { \
        int e = t * 8 + (i) * 2048; \
        int c = e >> 6, j = e & 63; \
        *(uint4*)&sm.p1.ws[c][j] = (v); \
    } while (0)

    LOADX(0);
    LOADW(0);

    for (int q = 0; q < 8; ++q) {
        __syncthreads();
        STX(0, xr0); STX(1, xr1); STX(2, xr2); STX(3, xr3);
        STW(0, wv0); STW(1, wv1); STW(2, wv2); STW(3, wv3);
        STW(4, wv4); STW(5, wv5); STW(6, wv6); STW(7, wv7);
        __syncthreads();
        if (q < 7) {
            LOADX(q + 1);
            LOADW(q + 1);
        }
#pragma unroll
        for (int s = 0; s < 2; ++s) {
            short8v a = *(const short8v*)&sm.p1.xs[wr0 + l15][s * 32 + l4 * 8];
#pragma unroll
            for (int tc = 0; tc < 16; ++tc) {
                short8v b = *(const short8v*)&sm.p1.ws[tc * 16 + l15][s * 32 + l4 * 8];
                acc[tc] = __builtin_amdgcn_mfma_f32_16x16x32_bf16(a, b, acc[tc], 0, 0, 0);
            }
        }
    }
    __syncthreads();  // xs/ws dead; p2 overlay begins

#pragma unroll
    for (int tc = 0; tc < 16; ++tc) {
        float bv = b1[tc * 16 + l15];
#pragma unroll
        for (int i = 0; i < 4; ++i) {
            float v = fmaxf(acc[tc][i] + bv, 0.f);
            sm.p2.hid[wr0 + l4 * 4 + i][tc * 16 + l15] = f2bf(v);
        }
    }

    f32x4 acc2[4];
#pragma unroll
    for (int i = 0; i < 4; ++i) acc2[i] = (f32x4){0.f, 0.f, 0.f, 0.f};

#pragma unroll
    for (int hf = 0; hf < 2; ++hf) {
#pragma unroll
        for (int i = 0; i < 4; ++i) {
            int e = t * 8 + i * 2048;
            int c = e >> 8, k = e & 255;
            *(uint4*)&sm.p2.w2s[c][k] = *(const uint4*)&w2p[hf * 8192 + e];
        }
        __syncthreads();
#pragma unroll
        for (int s = 0; s < 8; ++s) {
            short8v a = *(const short8v*)&sm.p2.hid[wr0 + l15][s * 32 + l4 * 8];
#pragma unroll
            for (int tcl = 0; tcl < 2; ++tcl) {
                short8v b = *(const short8v*)&sm.p2.w2s[tcl * 16 + l15][s * 32 + l4 * 8];
                acc2[hf * 2 + tcl] =
                    __builtin_amdgcn_mfma_f32_16x16x32_bf16(a, b, acc2[hf * 2 + tcl], 0, 0, 0);
            }
        }
        __syncthreads();
    }

    // epilogue2: zb = bf16(ALPHA*v), hs = fp8_e4m3(dinv*v)   [h0 fp32 eliminated]
#pragma unroll
    for (int i = 0; i < 4; ++i) {
        int row = row0 + wr0 + l4 * 4 + i;
        if (row < N) {
            float dv = dinv[row];
#pragma unroll
            for (int tc = 0; tc < 4; ++tc) {
                float v = acc2[tc][i] + b2[tc * 16 + l15];
                zb[(size_t)row * OUT_DIM + tc * 16 + l15] = f2bf(ALPHA * v);
                float sv = dv * v;
                int pk = __builtin_amdgcn_cvt_pk_fp8_f32(sv, sv, 0, false);
                hs[(size_t)row * OUT_DIM + tc * 16 + l15] = (unsigned char)(pk & 0xFF);
            }
        }
    }
#undef LOADX
#undef LOADW
#undef STX
#undef STW
}

// ---------------- propagation, fp8 rows, 8-lane/row (r19 structure) + bf16 z-term ----
// r20 lesson: 8B/lane is the payload sweet spot. r22: z = ALPHA*h0 stored bf16
// (one uint4 = 8 bf16 per lane) -> h0 fp32 stream gone.
__global__ __launch_bounds__(256) void prop_fp8_kernel(const unsigned char* __restrict__ hs,
                                                       const unsigned short* __restrict__ zb,
                                                       const float* __restrict__ dinv,
                                                       const int* __restrict__ csr_row,
                                                       const int* __restrict__ indptr,
                                                       unsigned char* __restrict__ hs_out,
                                                       float* __restrict__ hfin,
                                                       int last, int N) {
    int node = blockIdx.x * 4 + (threadIdx.x >> 6);
    if (node >= N) return;
    int l = threadIdx.x & 63;
    int q8 = l >> 3, lf8 = l & 7;
    const uint2* H2 = (const uint2*)hs;   // [N][8] uint2
    int beg = indptr[node], end = indptr[node + 1];
    float b0 = 0.f, b1v = 0.f, b2v = 0.f, b3 = 0.f;
    float b4 = 0.f, b5 = 0.f, b6 = 0.f, b7 = 0.f;
#define ACCU2(u2) do { \
        f32x2 _p0 = __builtin_amdgcn_cvt_pk_f32_fp8((int)(u2).x, false); \
        f32x2 _p1 = __builtin_amdgcn_cvt_pk_f32_fp8((int)(u2).x, true);  \
        f32x2 _p2 = __builtin_amdgcn_cvt_pk_f32_fp8((int)(u2).y, false); \
        f32x2 _p3 = __builtin_amdgcn_cvt_pk_f32_fp8((int)(u2).y, true);  \
        b0 += _p0[0]; b1v += _p0[1]; b2v += _p1[0]; b3 += _p1[1];        \
        b4 += _p2[0]; b5 += _p2[1]; b6 += _p3[0]; b7 += _p3[1];          \
    } while (0)
    int e = beg;
    for (; e + 32 <= end; e += 32) {   // 32 edges: 4 idx loads, 4 gathers (32 rows in flight)
        int r0 = csr_row[e + 0 + q8];
        int r1 = csr_row[e + 8 + q8];
        int r2 = csr_row[e + 16 + q8];
        int r3 = csr_row[e + 24 + q8];
        uint2 u0 = H2[(size_t)r0 * 8 + lf8];
        uint2 u1 = H2[(size_t)r1 * 8 + lf8];
        uint2 u2 = H2[(size_t)r2 * 8 + lf8];
        uint2 u3 = H2[(size_t)r3 * 8 + lf8];
        ACCU2(u0); ACCU2(u1); ACCU2(u2); ACCU2(u3);
    }
    for (; e + 8 <= end; e += 8) {
        int r = csr_row[e + q8];
        uint2 u = H2[(size_t)r * 8 + lf8];
        ACCU2(u);
    }
    if (e + q8 < end) {  // masked tail (<8 edges)
        int r = csr_row[e + q8];
        uint2 u = H2[(size_t)r * 8 + lf8];
        ACCU2(u);
    }
    // reduce across the 8 edge-slots (lane bits 3,4,5)
    b0 += __shfl_xor(b0, 8);  b1v += __shfl_xor(b1v, 8);
    b2v += __shfl_xor(b2v, 8); b3 += __shfl_xor(b3, 8);
    b4 += __shfl_xor(b4, 8);  b5 += __shfl_xor(b5, 8);
    b6 += __shfl_xor(b6, 8);  b7 += __shfl_xor(b7, 8);
    b0 += __shfl_xor(b0, 16); b1v += __shfl_xor(b1v, 16);
    b2v += __shfl_xor(b2v, 16); b3 += __shfl_xor(b3, 16);
    b4 += __shfl_xor(b4, 16); b5 += __shfl_xor(b5, 16);
    b6 += __shfl_xor(b6, 16); b7 += __shfl_xor(b7, 16);
    b0 += __shfl_xor(b0, 32); b1v += __shfl_xor(b1v, 32);
    b2v += __shfl_xor(b2v, 32); b3 += __shfl_xor(b3, 32);
    b4 += __shfl_xor(b4, 32); b5 += __shfl_xor(b5, 32);
    b6 += __shfl_xor(b6, 32); b7 += __shfl_xor(b7, 32);
    {
        uint2 us = H2[(size_t)node * 8 + lf8];  // self loop (post-reduce, uniform)
        ACCU2(us);
    }
#undef ACCU2
    float dcn = dinv[node];
    // z-term: 8 bf16 per lane (ALPHA pre-folded)
    uint4 zv = ((const uint4*)zb)[(size_t)node * 8 + lf8];
    float o0 = (1.0f - ALPHA) * (dcn * b0) + bflo(zv.x);
    float o1 = (1.0f - ALPHA) * (dcn * b1v) + bfhi(zv.x);
    float o2 = (1.0f - ALPHA) * (dcn * b2v) + bflo(zv.y);
    float o3 = (1.0f - ALPHA) * (dcn * b3) + bfhi(zv.y);
    float o4 = (1.0f - ALPHA) * (dcn * b4) + bflo(zv.z);
    float o5 = (1.0f - ALPHA) * (dcn * b5) + bfhi(zv.z);
    float o6 = (1.0f - ALPHA) * (dcn * b6) + bflo(zv.w);
    float o7 = (1.0f - ALPHA) * (dcn * b7) + bfhi(zv.w);
    if (last) {
        // fused log_softmax: row lives in the 8 lf8 lanes; xor {1,2,4} closed in-group
        float m = fmaxf(fmaxf(fmaxf(o0, o1), fmaxf(o2, o3)),
                        fmaxf(fmaxf(o4, o5), fmaxf(o6, o7)));
        m = fmaxf(m, __shfl_xor(m, 1));
        m = fmaxf(m, __shfl_xor(m, 2));
        m = fmaxf(m, __shfl_xor(m, 4));
        float s = expf(o0 - m) + expf(o1 - m) + expf(o2 - m) + expf(o3 - m) +
                  expf(o4 - m) + expf(o5 - m) + expf(o6 - m) + expf(o7 - m);
        s += __shfl_xor(s, 1);
        s += __shfl_xor(s, 2);
        s += __shfl_xor(s, 4);
        float lg = logf(s);
        if (q8 == 0) {
            float4 oa, ob;
            oa.x = o0 - m - lg; oa.y = o1 - m - lg; oa.z = o2 - m - lg; oa.w = o3 - m - lg;
            ob.x = o4 - m - lg; ob.y = o5 - m - lg; ob.z = o6 - m - lg; ob.w = o7 - m - lg;
            *(float4*)&hfin[(size_t)node * 64 + lf8 * 8] = oa;
            *(float4*)&hfin[(size_t)node * 64 + lf8 * 8 + 4] = ob;
        }
    } else if (q8 == 0) {
        int pk0 = __builtin_amdgcn_cvt_pk_fp8_f32(dcn * o0, dcn * o1, 0, false);
        pk0 = __builtin_amdgcn_cvt_pk_fp8_f32(dcn * o2, dcn * o3, pk0, true);
        int pk1 = __builtin_amdgcn_cvt_pk_fp8_f32(dcn * o4, dcn * o5, 0, false);
        pk1 = __builtin_amdgcn_cvt_pk_fp8_f32(dcn * o6, dcn * o7, pk1, true);
        ((uint2*)hs_out)[(size_t)node * 8 + lf8] = make_uint2((unsigned)pk0, (unsigned)pk1);
    }
}

extern "C" void kernel_launch(void* const* d_in, const int* in_sizes, int n_in,
                              void* d_out, int out_size, void* d_ws, size_t ws_size,
                              hipStream_t stream) {
    const float* x  = (const float*)d_in[0];
    const int*   ei = (const int*)d_in[1];
    const float* W1 = (const float*)d_in[2];
    const float* b1 = (const float*)d_in[3];
    const float* W2 = (const float*)d_in[4];
    const float* b2 = (const float*)d_in[5];
    float* out = (float*)d_out;
    int N = in_sizes[0] / IN_DIM;
    int E = in_sizes[1] / 2;
    int nbkt = (N + 511) >> BKT_SHIFT;

    char* ws = (char*)d_ws;
    size_t off = 0;
    auto alloc = [&](size_t bytes) -> void* {
        void* p = ws + off;
        off += (bytes + 255) & ~(size_t)255;
        return p;
    };
    unsigned short* zb = (unsigned short*)alloc((size_t)N * OUT_DIM * 2);  // bf16 ALPHA*h0
    float* dinv   = (float*)alloc((size_t)N * 4);
    int*   indptr = (int*)alloc((size_t)(N + 1) * 4);
    int*   bcnt   = (int*)alloc(256 * 4);
    int*   bbase  = (int*)alloc(256 * 4);
    int*   bfill  = (int*)alloc(256 * 4);
    int*   packed = (int*)alloc((size_t)E * 4);
    int*   csr_row= (int*)alloc((size_t)E * 4);
    unsigned short* w1p = (unsigned short*)alloc((size_t)IN_DIM * HID_DIM * 2);
    unsigned short* w2p = (unsigned short*)alloc((size_t)HID_DIM * OUT_DIM * 2);
    unsigned char* hsA = (unsigned char*)alloc((size_t)N * OUT_DIM);  // fp8
    unsigned char* hsB = (unsigned char*)alloc((size_t)N * OUT_DIM);  // fp8
    (void)ws_size; (void)n_in; (void)out_size;

    hipMemsetAsync(bcnt, 0, 256 * 4, stream);

    prep_w1_kernel<<<(IN_DIM * HID_DIM) / 256, 256, 0, stream>>>(W1, w1p);
    prep_w2_kernel<<<(HID_DIM * OUT_DIM) / 256, 256, 0, stream>>>(W2, w2p);

    int pgrid = (E + PART_EPB - 1) / PART_EPB;
    bucket_count_kernel<<<pgrid, 256, 0, stream>>>(ei, E, bcnt);
    bucket_scan_kernel<<<1, 256, 0, stream>>>(bcnt, bbase, bfill, indptr, E, N);
    partition_kernel<<<pgrid, 256, 0, stream>>>(ei, E, bfill, packed);
    fine_kernel<<<nbkt, 256, 0, stream>>>(packed, bbase, bcnt, csr_row, indptr, dinv, N);

    mlp_mfma_kernel<<<(N + 63) / 64, 256, 0, stream>>>(x, w1p, b1, w2p, b2, dinv,
                                                       zb, hsA, N);

    int pb = (N + 3) / 4;
    for (int it = 0; it < KPROP; ++it) {
        const unsigned char* hin = (it % 2 == 0) ? hsA : hsB;
        unsigned char* hout = (it % 2 == 0) ? hsB : hsA;
        int last = (it == KPROP - 1) ? 1 : 0;
        prop_fp8_kernel<<<pb, 256, 0, stream>>>(hin, zb, dinv, csr_row, indptr,
                                                hout, out, last, N);
    }
}